// Round 1
// baseline (21010.164 us; speedup 1.0000x reference)
//
#include <hip/hip_runtime.h>

#define NNODES 200000
#define NEDGES 6400000
#define NENT   2048
#define CH     8
#define HID    32
#define NCONV  8
#define BN_EPS 1e-5f

// ---------------- degree / normalization ----------------
__global__ __launch_bounds__(256) void k_deg(const int* __restrict__ dst, int* __restrict__ deg, int E){
  int stride = gridDim.x*blockDim.x;
  for(int e = blockIdx.x*blockDim.x + threadIdx.x; e < E; e += stride)
    atomicAdd(&deg[dst[e]], 1);
}

// in-place: buffer holds int counts, becomes float 1/sqrt(count+1)
__global__ __launch_bounds__(256) void k_dinv(float* __restrict__ buf, int N){
  int i = blockIdx.x*blockDim.x + threadIdx.x;
  if(i < N){
    int c = __float_as_int(buf[i]);            // stored bit-pattern is an int count
    buf[i] = 1.0f / sqrtf((float)c + 1.0f);
  }
}

// ---------------- h init: embedding gather ----------------
__global__ __launch_bounds__(256) void k_init_h(const int* __restrict__ x, const float* __restrict__ emb,
                                                float* __restrict__ h, int N){
  int i = blockIdx.x*blockDim.x + threadIdx.x;
  if(i < N){
    int t = x[i];
    const float4* ep = (const float4*)(emb + (size_t)t*CH);
    float4 a = ep[0], b = ep[1];
    float4* hp = (float4*)(h + (size_t)i*CH);
    hp[0] = a; hp[1] = b;
  }
}

// ---------------- BN batch stats (sum, sumsq per channel) ----------------
__global__ __launch_bounds__(256) void k_stats(const float* __restrict__ h, double* __restrict__ stats, int N){
  float s[CH], q[CH];
  #pragma unroll
  for(int c=0;c<CH;c++){ s[c]=0.f; q[c]=0.f; }
  int stride = gridDim.x*blockDim.x;
  for(int i = blockIdx.x*blockDim.x + threadIdx.x; i < N; i += stride){
    const float4* hp = (const float4*)(h + (size_t)i*CH);
    float4 a = hp[0], b = hp[1];
    float v[CH] = {a.x,a.y,a.z,a.w,b.x,b.y,b.z,b.w};
    #pragma unroll
    for(int c=0;c<CH;c++){ s[c]+=v[c]; q[c]+=v[c]*v[c]; }
  }
  #pragma unroll
  for(int off=32; off>0; off>>=1){
    #pragma unroll
    for(int c=0;c<CH;c++){
      s[c] += __shfl_down(s[c], off);
      q[c] += __shfl_down(q[c], off);
    }
  }
  __shared__ float ls[4][2*CH];
  int wave = threadIdx.x>>6, lane = threadIdx.x&63;
  if(lane==0){
    #pragma unroll
    for(int c=0;c<CH;c++){ ls[wave][c]=s[c]; ls[wave][CH+c]=q[c]; }
  }
  __syncthreads();
  if(threadIdx.x < 2*CH){
    float t = ls[0][threadIdx.x]+ls[1][threadIdx.x]+ls[2][threadIdx.x]+ls[3][threadIdx.x];
    unsafeAtomicAdd(&stats[threadIdx.x], (double)t);
  }
}

// ---------------- fold BN into 8x8 affine: ht = h@A + c0 ----------------
__global__ void k_fold(const double* __restrict__ stats, const float* __restrict__ gamma,
                       const float* __restrict__ beta, const float* __restrict__ convw,
                       float* __restrict__ Af, int l){
  const double invN = 1.0 / (double)NNODES;
  float sarr[CH], tarr[CH];
  #pragma unroll
  for(int c=0;c<CH;c++){
    float mu  = (float)(stats[c]    * invN);
    float ex2 = (float)(stats[CH+c] * invN);
    float var = ex2 - mu*mu;
    float r   = 1.0f / sqrtf(var + BN_EPS);
    float sc  = r * gamma[l*CH+c];
    sarr[c] = sc;
    tarr[c] = beta[l*CH+c] - mu*sc;
  }
  int tid = threadIdx.x;
  if(tid < CH*CH){
    int ci = tid>>3, co = tid&7;
    Af[tid] = sarr[ci] * convw[(l*CH+ci)*CH+co];
  }
  if(tid < CH){
    float a = 0.f;
    #pragma unroll
    for(int ci=0;ci<CH;ci++) a += tarr[ci]*convw[(l*CH+ci)*CH+tid];
    Af[CH*CH+tid] = a;
  }
}

// ---------------- per-node transform + acc init ----------------
// ht = h@A + c0 ; acc = h + ht*dinv^2 + conv_b   (edge kernel then adds neighbor terms)
__global__ __launch_bounds__(256) void k_ht(const float* __restrict__ h, const float* __restrict__ Af,
                                            const float* __restrict__ convb, const float* __restrict__ dinv,
                                            float* __restrict__ ht, float* __restrict__ acc, int l, int N){
  __shared__ float A[CH*CH], c0[CH], bb[CH];
  if(threadIdx.x < CH*CH) A[threadIdx.x] = Af[threadIdx.x];
  if(threadIdx.x < CH){ c0[threadIdx.x] = Af[CH*CH+threadIdx.x]; bb[threadIdx.x] = convb[l*CH+threadIdx.x]; }
  __syncthreads();
  int i = blockIdx.x*blockDim.x + threadIdx.x;
  if(i >= N) return;
  const float4* hp = (const float4*)(h + (size_t)i*CH);
  float4 a = hp[0], b = hp[1];
  float v[CH] = {a.x,a.y,a.z,a.w,b.x,b.y,b.z,b.w};
  float o[CH];
  #pragma unroll
  for(int co=0;co<CH;co++) o[co]=c0[co];
  #pragma unroll
  for(int ci=0;ci<CH;ci++){
    float vv = v[ci];
    #pragma unroll
    for(int co=0;co<CH;co++) o[co] += vv*A[ci*CH+co];
  }
  float4* hto = (float4*)(ht + (size_t)i*CH);
  hto[0] = make_float4(o[0],o[1],o[2],o[3]);
  hto[1] = make_float4(o[4],o[5],o[6],o[7]);
  float dn = dinv[i];
  float sn = dn*dn;
  float r[CH];
  #pragma unroll
  for(int c=0;c<CH;c++) r[c] = v[c] + o[c]*sn + bb[c];
  float4* ao = (float4*)(acc + (size_t)i*CH);
  ao[0] = make_float4(r[0],r[1],r[2],r[3]);
  ao[1] = make_float4(r[4],r[5],r[6],r[7]);
}

// ---------------- edge aggregation (push, fp32 atomics) ----------------
__global__ __launch_bounds__(256) void k_edge(const int* __restrict__ src, const int* __restrict__ dst,
                                              const float* __restrict__ dinv, const float* __restrict__ ht,
                                              float* __restrict__ acc, int E){
  int stride = gridDim.x*blockDim.x;
  for(int e = blockIdx.x*blockDim.x + threadIdx.x; e < E; e += stride){
    int s = src[e], d = dst[e];
    float w = dinv[s]*dinv[d];
    const float4* hp = (const float4*)(ht + (size_t)s*CH);
    float4 a = hp[0], b = hp[1];
    float* ap = acc + (size_t)d*CH;
    unsafeAtomicAdd(ap+0, a.x*w);
    unsafeAtomicAdd(ap+1, a.y*w);
    unsafeAtomicAdd(ap+2, a.z*w);
    unsafeAtomicAdd(ap+3, a.w*w);
    unsafeAtomicAdd(ap+4, b.x*w);
    unsafeAtomicAdd(ap+5, b.y*w);
    unsafeAtomicAdd(ap+6, b.z*w);
    unsafeAtomicAdd(ap+7, b.w*w);
  }
}

// ---------------- residual already in acc; apply ReLU -> new h ----------------
__global__ __launch_bounds__(256) void k_relu(const float* __restrict__ acc, float* __restrict__ h, int n4){
  int i = blockIdx.x*blockDim.x + threadIdx.x;
  if(i < n4){
    float4 a = ((const float4*)acc)[i];
    a.x = fmaxf(a.x, 0.f); a.y = fmaxf(a.y, 0.f);
    a.z = fmaxf(a.z, 0.f); a.w = fmaxf(a.w, 0.f);
    ((float4*)h)[i] = a;
  }
}

// ---------------- entries: u = xe@W1, v = xe@W2 + hb ----------------
__global__ __launch_bounds__(256) void k_uv(const int* __restrict__ entry, const float* __restrict__ h,
                                            const float* __restrict__ hw, const float* __restrict__ hb,
                                            float* __restrict__ u, float* __restrict__ v){
  __shared__ float w[2*CH*HID];
  __shared__ float b[HID];
  for(int t=threadIdx.x; t<2*CH*HID; t+=256) w[t]=hw[t];
  if(threadIdx.x<HID) b[threadIdx.x]=hb[threadIdx.x];
  __syncthreads();
  int k = blockIdx.x*blockDim.x + threadIdx.x;
  if(k >= NENT) return;
  int node = entry[k];
  const float4* hp = (const float4*)(h + (size_t)node*CH);
  float4 a = hp[0], b4 = hp[1];
  float xe[CH] = {a.x,a.y,a.z,a.w,b4.x,b4.y,b4.z,b4.w};
  #pragma unroll 4
  for(int c=0;c<HID;c++){
    float uu = 0.f, vv = b[c];
    #pragma unroll
    for(int ci=0;ci<CH;ci++){
      uu += xe[ci]*w[ci*HID+c];
      vv += xe[ci]*w[(CH+ci)*HID+c];
    }
    u[(size_t)k*HID+c] = uu;
    v[(size_t)k*HID+c] = vv;
  }
}

// ---------------- pairwise scorer: out[i,j] = sum_c relu(u[i,c]+v[j,c])*ow[c] + ob ----------------
// block = 256 threads covers a 16(i) x 64(j) tile; thread (ty,tx) computes 4 i's.
__global__ __launch_bounds__(256) void k_pair(const float* __restrict__ u, const float* __restrict__ v,
                                              const float* __restrict__ ow, const float* __restrict__ ob,
                                              float* __restrict__ out){
  __shared__ float us[16][HID+1];
  __shared__ float vs[64][HID+1];
  __shared__ float wo[HID];
  int tid = threadIdx.x;
  int jb = blockIdx.x*64, ib = blockIdx.y*16;
  for(int t=tid; t<16*HID; t+=256) us[t>>5][t&31] = u[(size_t)(ib + (t>>5))*HID + (t&31)];
  for(int t=tid; t<64*HID; t+=256) vs[t>>5][t&31] = v[(size_t)(jb + (t>>5))*HID + (t&31)];
  if(tid<HID) wo[tid]=ow[tid];
  __syncthreads();
  int tx = tid&63, ty = tid>>6;
  float a0=0.f, a1=0.f, a2=0.f, a3=0.f;
  #pragma unroll
  for(int c=0;c<HID;c++){
    float vv = vs[tx][c];
    float w  = wo[c];
    a0 += fmaxf(us[ty   ][c]+vv, 0.f)*w;
    a1 += fmaxf(us[ty+4 ][c]+vv, 0.f)*w;
    a2 += fmaxf(us[ty+8 ][c]+vv, 0.f)*w;
    a3 += fmaxf(us[ty+12][c]+vv, 0.f)*w;
  }
  float o0 = ob[0];
  size_t base = (size_t)ib*2048 + jb + tx;
  out[base + (size_t)(ty   )*2048] = a0+o0;
  out[base + (size_t)(ty+4 )*2048] = a1+o0;
  out[base + (size_t)(ty+8 )*2048] = a2+o0;
  out[base + (size_t)(ty+12)*2048] = a3+o0;
}

extern "C" void kernel_launch(void* const* d_in, const int* in_sizes, int n_in,
                              void* d_out, int out_size, void* d_ws, size_t ws_size,
                              hipStream_t stream){
  const int*   x     = (const int*)d_in[0];
  const int*   ei    = (const int*)d_in[1];
  const int*   entry = (const int*)d_in[2];
  const float* emb   = (const float*)d_in[3];
  const float* gamma = (const float*)d_in[4];
  const float* beta  = (const float*)d_in[5];
  const float* convw = (const float*)d_in[6];
  const float* convb = (const float*)d_in[7];
  const float* hw    = (const float*)d_in[8];
  const float* hb    = (const float*)d_in[9];
  const float* ow    = (const float*)d_in[10];
  const float* ob    = (const float*)d_in[11];
  const int* srcp = ei;
  const int* dstp = ei + NEDGES;

  // workspace layout (~20.5 MB)
  char* ws = (char*)d_ws;
  size_t o = 0;
  float*  dinv  = (float*)(ws + o);  o += 800256;                  // N*4 padded to 256
  float*  h     = (float*)(ws + o);  o += (size_t)NNODES*CH*4;     // 6,400,000
  float*  htb   = (float*)(ws + o);  o += (size_t)NNODES*CH*4;
  float*  accb  = (float*)(ws + o);  o += (size_t)NNODES*CH*4;
  double* stats = (double*)(ws + o); o += 256;
  float*  Af    = (float*)(ws + o);  o += 256;
  float*  ub    = (float*)(ws + o);  o += (size_t)NENT*HID*4;
  float*  vb    = (float*)(ws + o);  o += (size_t)NENT*HID*4;
  (void)ws_size; (void)in_sizes; (void)n_in; (void)out_size;

  hipMemsetAsync(dinv, 0, NNODES*sizeof(int), stream);
  k_deg   <<<4096, 256, 0, stream>>>(dstp, (int*)dinv, NEDGES);
  k_dinv  <<<(NNODES+255)/256, 256, 0, stream>>>(dinv, NNODES);
  k_init_h<<<(NNODES+255)/256, 256, 0, stream>>>(x, emb, h, NNODES);

  for(int l=0; l<NCONV; l++){
    hipMemsetAsync(stats, 0, 2*CH*sizeof(double), stream);
    k_stats<<<256, 256, 0, stream>>>(h, stats, NNODES);
    k_fold <<<1, 64, 0, stream>>>(stats, gamma, beta, convw, Af, l);
    k_ht   <<<(NNODES+255)/256, 256, 0, stream>>>(h, Af, convb, dinv, htb, accb, l, NNODES);
    k_edge <<<4096, 256, 0, stream>>>(srcp, dstp, dinv, htb, accb, NEDGES);
    k_relu <<<(NNODES*CH/4+255)/256, 256, 0, stream>>>(accb, h, NNODES*CH/4);
  }

  k_uv<<<NENT/256, 256, 0, stream>>>(entry, h, hw, hb, ub, vb);
  dim3 pg(2048/64, 2048/16);
  k_pair<<<pg, 256, 0, stream>>>(ub, vb, ow, ob, (float*)d_out);
}

// Round 2
// 1553.852 us; speedup vs baseline: 13.5213x; 13.5213x over previous
//
#include <hip/hip_runtime.h>

#define NNODES 200000
#define NEDGES 6400000
#define NENT   2048
#define CH     8
#define HID    32
#define NCONV  8
#define BN_EPS 1e-5f

#define SCAN_B 1024
#define NBLK   ((NNODES + SCAN_B - 1) / SCAN_B)   // 196

// ---------------- degree count ----------------
__global__ __launch_bounds__(256) void k_deg(const int* __restrict__ dst, int* __restrict__ deg, int E){
  int stride = gridDim.x*blockDim.x;
  for(int e = blockIdx.x*blockDim.x + threadIdx.x; e < E; e += stride)
    atomicAdd(&deg[dst[e]], 1);
}

// dinv[i] = 1/sqrt(deg[i]+1)
__global__ __launch_bounds__(256) void k_dinv(const int* __restrict__ deg, float* __restrict__ dinv, int N){
  int i = blockIdx.x*blockDim.x + threadIdx.x;
  if(i < N) dinv[i] = 1.0f / sqrtf((float)deg[i] + 1.0f);
}

// ---------------- prefix scan of degrees -> csr_off ----------------
__global__ __launch_bounds__(SCAN_B) void k_scan1(const int* __restrict__ deg, int* __restrict__ bsum, int N){
  __shared__ int sd[SCAN_B];
  int i = blockIdx.x*SCAN_B + threadIdx.x;
  sd[threadIdx.x] = (i < N) ? deg[i] : 0;
  __syncthreads();
  for(int off = SCAN_B/2; off > 0; off >>= 1){
    if(threadIdx.x < off) sd[threadIdx.x] += sd[threadIdx.x + off];
    __syncthreads();
  }
  if(threadIdx.x == 0) bsum[blockIdx.x] = sd[0];
}

__global__ __launch_bounds__(256) void k_scan2(int* __restrict__ bsum, int nb){
  __shared__ int sd[256];
  int t = threadIdx.x;
  int v = (t < nb) ? bsum[t] : 0;
  sd[t] = v; __syncthreads();
  for(int o = 1; o < 256; o <<= 1){
    int x = (t >= o) ? sd[t-o] : 0;
    __syncthreads();
    sd[t] += x;
    __syncthreads();
  }
  if(t < nb) bsum[t] = sd[t] - v;   // exclusive
}

__global__ __launch_bounds__(SCAN_B) void k_scan3(const int* __restrict__ deg, const int* __restrict__ bsum,
                                                  int* __restrict__ off, int* __restrict__ cursor, int N){
  __shared__ int sd[SCAN_B];
  int i = blockIdx.x*SCAN_B + threadIdx.x;
  int v = (i < N) ? deg[i] : 0;
  sd[threadIdx.x] = v;
  __syncthreads();
  for(int o = 1; o < SCAN_B; o <<= 1){
    int x = (threadIdx.x >= o) ? sd[threadIdx.x - o] : 0;
    __syncthreads();
    sd[threadIdx.x] += x;
    __syncthreads();
  }
  int excl = bsum[blockIdx.x] + sd[threadIdx.x] - v;
  if(i < N){ off[i] = excl; cursor[i] = excl; }
  if(i == N-1) off[N] = excl + v;
}

// ---------------- scatter edges into CSR (sorted by dst) ----------------
__global__ __launch_bounds__(256) void k_scatter(const int* __restrict__ src, const int* __restrict__ dst,
                                                 int* __restrict__ cursor, int* __restrict__ csrc, int E){
  int stride = gridDim.x*blockDim.x;
  for(int e = blockIdx.x*blockDim.x + threadIdx.x; e < E; e += stride){
    int d = dst[e];
    int pos = atomicAdd(&cursor[d], 1);
    csrc[pos] = src[e];
  }
}

// ---------------- h init: embedding gather ----------------
__global__ __launch_bounds__(256) void k_init_h(const int* __restrict__ x, const float* __restrict__ emb,
                                                float* __restrict__ h, int N){
  int i = blockIdx.x*blockDim.x + threadIdx.x;
  if(i < N){
    int t = x[i];
    const float4* ep = (const float4*)(emb + (size_t)t*CH);
    float4 a = ep[0], b = ep[1];
    float4* hp = (float4*)(h + (size_t)i*CH);
    hp[0] = a; hp[1] = b;
  }
}

// ---------------- BN batch stats (sum, sumsq per channel) ----------------
__global__ __launch_bounds__(256) void k_stats(const float* __restrict__ h, double* __restrict__ stats, int N){
  float s[CH], q[CH];
  #pragma unroll
  for(int c=0;c<CH;c++){ s[c]=0.f; q[c]=0.f; }
  int stride = gridDim.x*blockDim.x;
  for(int i = blockIdx.x*blockDim.x + threadIdx.x; i < N; i += stride){
    const float4* hp = (const float4*)(h + (size_t)i*CH);
    float4 a = hp[0], b = hp[1];
    float v[CH] = {a.x,a.y,a.z,a.w,b.x,b.y,b.z,b.w};
    #pragma unroll
    for(int c=0;c<CH;c++){ s[c]+=v[c]; q[c]+=v[c]*v[c]; }
  }
  #pragma unroll
  for(int off=32; off>0; off>>=1){
    #pragma unroll
    for(int c=0;c<CH;c++){
      s[c] += __shfl_down(s[c], off);
      q[c] += __shfl_down(q[c], off);
    }
  }
  __shared__ float ls[4][2*CH];
  int wave = threadIdx.x>>6, lane = threadIdx.x&63;
  if(lane==0){
    #pragma unroll
    for(int c=0;c<CH;c++){ ls[wave][c]=s[c]; ls[wave][CH+c]=q[c]; }
  }
  __syncthreads();
  if(threadIdx.x < 2*CH){
    float t = ls[0][threadIdx.x]+ls[1][threadIdx.x]+ls[2][threadIdx.x]+ls[3][threadIdx.x];
    unsafeAtomicAdd(&stats[threadIdx.x], (double)t);
  }
}

// ---------------- fold BN into 8x8 affine ----------------
__global__ void k_fold(const double* __restrict__ stats, const float* __restrict__ gamma,
                       const float* __restrict__ beta, const float* __restrict__ convw,
                       float* __restrict__ Af, int l){
  const double invN = 1.0 / (double)NNODES;
  float sarr[CH], tarr[CH];
  #pragma unroll
  for(int c=0;c<CH;c++){
    float mu  = (float)(stats[c]    * invN);
    float ex2 = (float)(stats[CH+c] * invN);
    float var = ex2 - mu*mu;
    float r   = 1.0f / sqrtf(var + BN_EPS);
    float sc  = r * gamma[l*CH+c];
    sarr[c] = sc;
    tarr[c] = beta[l*CH+c] - mu*sc;
  }
  int tid = threadIdx.x;
  if(tid < CH*CH){
    int ci = tid>>3, co = tid&7;
    Af[tid] = sarr[ci] * convw[(l*CH+ci)*CH+co];
  }
  if(tid < CH){
    float a = 0.f;
    #pragma unroll
    for(int ci=0;ci<CH;ci++) a += tarr[ci]*convw[(l*CH+ci)*CH+tid];
    Af[CH*CH+tid] = a;
  }
}

// ---------------- per-node transform: hts = (h@A + c0) * dinv ----------------
__global__ __launch_bounds__(256) void k_ht(const float* __restrict__ h, const float* __restrict__ Af,
                                            const float* __restrict__ dinv,
                                            float* __restrict__ hts, int N){
  __shared__ float A[CH*CH], c0[CH];
  if(threadIdx.x < CH*CH) A[threadIdx.x] = Af[threadIdx.x];
  if(threadIdx.x < CH) c0[threadIdx.x] = Af[CH*CH+threadIdx.x];
  __syncthreads();
  int i = blockIdx.x*blockDim.x + threadIdx.x;
  if(i >= N) return;
  const float4* hp = (const float4*)(h + (size_t)i*CH);
  float4 a = hp[0], b = hp[1];
  float v[CH] = {a.x,a.y,a.z,a.w,b.x,b.y,b.z,b.w};
  float o[CH];
  #pragma unroll
  for(int co=0;co<CH;co++) o[co]=c0[co];
  #pragma unroll
  for(int ci=0;ci<CH;ci++){
    float vv = v[ci];
    #pragma unroll
    for(int co=0;co<CH;co++) o[co] += vv*A[ci*CH+co];
  }
  float dn = dinv[i];
  float4* ho = (float4*)(hts + (size_t)i*CH);
  ho[0] = make_float4(o[0]*dn,o[1]*dn,o[2]*dn,o[3]*dn);
  ho[1] = make_float4(o[4]*dn,o[5]*dn,o[6]*dn,o[7]*dn);
}

// ---------------- pull aggregation + residual + ReLU (fused) ----------------
// 8 lanes per node; lane c owns channel c. No atomics.
// h_new[d,c] = relu( h[d,c] + conv_b[c] + dinv[d]*(hts[d,c] + sum_{s in N(d)} hts[s,c]) )
__global__ __launch_bounds__(256) void k_pull(const int* __restrict__ off, const int* __restrict__ csrc,
                                              const float* __restrict__ hts, const float* __restrict__ dinv,
                                              const float* __restrict__ convb,
                                              float* __restrict__ h, int l, int N){
  int tid = blockIdx.x*256 + threadIdx.x;
  int node = tid >> 3;
  int lane = tid & 7;
  if(node >= N) return;
  int s0 = off[node], s1 = off[node+1];
  float sum = hts[(size_t)node*CH + lane];      // self loop (premultiplied by dinv[node])
  int e = s0;
  for(; e + 4 <= s1; e += 4){
    int sa = csrc[e], sb = csrc[e+1], sc = csrc[e+2], sd = csrc[e+3];
    float va = hts[(size_t)sa*CH + lane];
    float vb = hts[(size_t)sb*CH + lane];
    float vc = hts[(size_t)sc*CH + lane];
    float vd = hts[(size_t)sd*CH + lane];
    sum += va + vb + vc + vd;
  }
  for(; e < s1; e++) sum += hts[(size_t)csrc[e]*CH + lane];
  float r = h[(size_t)node*CH + lane] + convb[l*CH + lane] + dinv[node]*sum;
  h[(size_t)node*CH + lane] = fmaxf(r, 0.f);
}

// ---------------- entries: u = xe@W1, v = xe@W2 + hb ----------------
__global__ __launch_bounds__(256) void k_uv(const int* __restrict__ entry, const float* __restrict__ h,
                                            const float* __restrict__ hw, const float* __restrict__ hb,
                                            float* __restrict__ u, float* __restrict__ v){
  __shared__ float w[2*CH*HID];
  __shared__ float b[HID];
  for(int t=threadIdx.x; t<2*CH*HID; t+=256) w[t]=hw[t];
  if(threadIdx.x<HID) b[threadIdx.x]=hb[threadIdx.x];
  __syncthreads();
  int k = blockIdx.x*blockDim.x + threadIdx.x;
  if(k >= NENT) return;
  int node = entry[k];
  const float4* hp = (const float4*)(h + (size_t)node*CH);
  float4 a = hp[0], b4 = hp[1];
  float xe[CH] = {a.x,a.y,a.z,a.w,b4.x,b4.y,b4.z,b4.w};
  #pragma unroll 4
  for(int c=0;c<HID;c++){
    float uu = 0.f, vv = b[c];
    #pragma unroll
    for(int ci=0;ci<CH;ci++){
      uu += xe[ci]*w[ci*HID+c];
      vv += xe[ci]*w[(CH+ci)*HID+c];
    }
    u[(size_t)k*HID+c] = uu;
    v[(size_t)k*HID+c] = vv;
  }
}

// ---------------- pairwise scorer ----------------
__global__ __launch_bounds__(256) void k_pair(const float* __restrict__ u, const float* __restrict__ v,
                                              const float* __restrict__ ow, const float* __restrict__ ob,
                                              float* __restrict__ out){
  __shared__ float us[16][HID+1];
  __shared__ float vs[64][HID+1];
  __shared__ float wo[HID];
  int tid = threadIdx.x;
  int jb = blockIdx.x*64, ib = blockIdx.y*16;
  for(int t=tid; t<16*HID; t+=256) us[t>>5][t&31] = u[(size_t)(ib + (t>>5))*HID + (t&31)];
  for(int t=tid; t<64*HID; t+=256) vs[t>>5][t&31] = v[(size_t)(jb + (t>>5))*HID + (t&31)];
  if(tid<HID) wo[tid]=ow[tid];
  __syncthreads();
  int tx = tid&63, ty = tid>>6;
  float a0=0.f, a1=0.f, a2=0.f, a3=0.f;
  #pragma unroll
  for(int c=0;c<HID;c++){
    float vv = vs[tx][c];
    float w  = wo[c];
    a0 += fmaxf(us[ty   ][c]+vv, 0.f)*w;
    a1 += fmaxf(us[ty+4 ][c]+vv, 0.f)*w;
    a2 += fmaxf(us[ty+8 ][c]+vv, 0.f)*w;
    a3 += fmaxf(us[ty+12][c]+vv, 0.f)*w;
  }
  float o0 = ob[0];
  size_t base = (size_t)ib*2048 + jb + tx;
  out[base + (size_t)(ty   )*2048] = a0+o0;
  out[base + (size_t)(ty+4 )*2048] = a1+o0;
  out[base + (size_t)(ty+8 )*2048] = a2+o0;
  out[base + (size_t)(ty+12)*2048] = a3+o0;
}

extern "C" void kernel_launch(void* const* d_in, const int* in_sizes, int n_in,
                              void* d_out, int out_size, void* d_ws, size_t ws_size,
                              hipStream_t stream){
  const int*   x     = (const int*)d_in[0];
  const int*   ei    = (const int*)d_in[1];
  const int*   entry = (const int*)d_in[2];
  const float* emb   = (const float*)d_in[3];
  const float* gamma = (const float*)d_in[4];
  const float* beta  = (const float*)d_in[5];
  const float* convw = (const float*)d_in[6];
  const float* convb = (const float*)d_in[7];
  const float* hw    = (const float*)d_in[8];
  const float* hb    = (const float*)d_in[9];
  const float* ow    = (const float*)d_in[10];
  const float* ob    = (const float*)d_in[11];
  const int* srcp = ei;
  const int* dstp = ei + NEDGES;

  // workspace layout (~43 MB)
  char* ws = (char*)d_ws;
  size_t o = 0;
  auto alloc = [&](size_t bytes){ void* p = ws + o; o += (bytes + 255) & ~(size_t)255; return p; };
  int*    deg    = (int*)   alloc(NNODES*4);
  float*  dinv   = (float*) alloc(NNODES*4);
  int*    csr_off= (int*)   alloc((NNODES+1)*4);
  int*    cursor = (int*)   alloc(NNODES*4);
  int*    bsum   = (int*)   alloc(NBLK*4);
  int*    csrc   = (int*)   alloc((size_t)NEDGES*4);
  float*  h      = (float*) alloc((size_t)NNODES*CH*4);
  float*  hts    = (float*) alloc((size_t)NNODES*CH*4);
  double* stats  = (double*)alloc(2*CH*8);
  float*  Af     = (float*) alloc((CH*CH+CH)*4);
  float*  ub     = (float*) alloc((size_t)NENT*HID*4);
  float*  vb     = (float*) alloc((size_t)NENT*HID*4);
  (void)ws_size; (void)in_sizes; (void)n_in; (void)out_size;

  // ---- CSR build (once per call) ----
  hipMemsetAsync(deg, 0, NNODES*sizeof(int), stream);
  k_deg    <<<4096, 256, 0, stream>>>(dstp, deg, NEDGES);
  k_dinv   <<<(NNODES+255)/256, 256, 0, stream>>>(deg, dinv, NNODES);
  k_scan1  <<<NBLK, SCAN_B, 0, stream>>>(deg, bsum, NNODES);
  k_scan2  <<<1, 256, 0, stream>>>(bsum, NBLK);
  k_scan3  <<<NBLK, SCAN_B, 0, stream>>>(deg, bsum, csr_off, cursor, NNODES);
  k_scatter<<<4096, 256, 0, stream>>>(srcp, dstp, cursor, csrc, NEDGES);

  k_init_h<<<(NNODES+255)/256, 256, 0, stream>>>(x, emb, h, NNODES);

  for(int l=0; l<NCONV; l++){
    hipMemsetAsync(stats, 0, 2*CH*sizeof(double), stream);
    k_stats<<<256, 256, 0, stream>>>(h, stats, NNODES);
    k_fold <<<1, 64, 0, stream>>>(stats, gamma, beta, convw, Af, l);
    k_ht   <<<(NNODES+255)/256, 256, 0, stream>>>(h, Af, dinv, hts, NNODES);
    k_pull <<<(NNODES*CH+255)/256, 256, 0, stream>>>(csr_off, csrc, hts, dinv, convb, h, l, NNODES);
  }

  k_uv<<<NENT/256, 256, 0, stream>>>(entry, h, hw, hb, ub, vb);
  dim3 pg(2048/64, 2048/16);
  k_pair<<<pg, 256, 0, stream>>>(ub, vb, ow, ob, (float*)d_out);
}